// Round 10
// baseline (28.242 us; speedup 1.0000x reference)
//
#include <hip/hip_runtime.h>

// Grouped conv1d over W + roll(+1) along H, bf16 MFMA 16x16x32.
// x: (128, 48, 28, 28) f32, channel = g*24+ci
// w: (24, 96, 7) f32, w[ci][o][k], shared across the 2 groups
// out: (128, 192, 28, 28) f32, channel = g*96+o
//
// R10: 1792 one-tile blocks (b,g,ht) x 384 thr, LDS = 6.9KB xs only ->
// 4-5 blocks (24-30 waves)/CU resident; inter-block overlap replaces the
// persistent pipeline (R9 lesson: 12 lockstep waves/CU leave HBM at 40%).
// wf precomputed in d_ws (R5-proven), B operand = 24 VGPR via 6 L2-hot
// dwordx4. Aligned-row float4 epilogue (R6/R7: measured ideal WRITE 75.3MB).
// v_cvt_pk_bf16_f32 replaces hand-rolled f2bf in staging (~9 VALU -> 1).
//
// GEMM per tile: M=112 (4 output rows x 28 W), N=96, K=168 pad 192.
// k-permutation (A and B must match): q = ks*4+kgrp (0..23);
//   q<21: k=q/3, ci=(q%3)*8+j ; q>=21: zero (B side).
// Block owns OUTPUT rows 4ht..4ht+3; src rows (4ht+hl-1) mod 28 absorb roll.

typedef __attribute__((ext_vector_type(8))) short short8;
typedef __attribute__((ext_vector_type(4))) float float4v;

#define B_     128
#define H_     28
#define W_     28
#define CIN_   24
#define COUT_  96
#define K_     7
#define KSTEPS 6
#define NT_    6
#define MT_    7
#define HW_    784

// float -> bf16 bits, RNE (cold path: wfrag kernel only)
static __device__ __forceinline__ short f2bf(float f) {
    union { float f; unsigned u; } v; v.f = f;
    return (short)((v.u + 0x7fffu + ((v.u >> 16) & 1u)) >> 16);
}

// packed 2x f32 -> bf16x2 in one instruction (lo <- a, hi <- b)
static __device__ __forceinline__ unsigned cvt_pk_bf16(float a, float b) {
    unsigned r;
    asm("v_cvt_pk_bf16_f32 %0, %1, %2" : "=v"(r) : "v"(a), "v"(b));
    return r;
}

// Pre-pack weights into B-fragment order with the permuted k-axis.
// B-frag (16x16x32): lane l holds B[hw=(l>>4)*8+j][col=l&15], j=0..7
__global__ __launch_bounds__(64)
void wfrag_kernel(const float* __restrict__ w, short8* __restrict__ wf) {
    const int idx  = blockIdx.x;          // 0..35 = ks*6 + nt
    const int ks   = idx / 6, nt = idx - ks * 6;
    const int lane = threadIdx.x;
    const int c    = nt * 16 + (lane & 15);
    const int q    = ks * 4 + (lane >> 4);
    short8 v;
    if (q < 21) {
        const int k   = (q * 11) >> 5;    // q/3 for q in 0..23
        const int ci0 = (q - 3 * k) * 8;
#pragma unroll
        for (int j = 0; j < 8; ++j)
            v[j] = f2bf(w[(ci0 + j) * (COUT_ * K_) + c * K_ + k]);
    } else {
#pragma unroll
        for (int j = 0; j < 8; ++j) v[j] = 0;   // zero-pad K (A garbage harmless)
    }
    wf[idx * 64 + lane] = v;
}

__global__ __launch_bounds__(384, 6)
void conv_mfma_kernel(const float* __restrict__ x,
                      const short8* __restrict__ wfg,
                      float* __restrict__ out) {
    const int bid = blockIdx.x;           // (b*2+g)*7 + ht
    const int ht  = bid % 7;
    const int bg  = bid / 7;
    const int g   = bg & 1;
    const int b   = bg >> 1;
    const int tid  = threadIdx.x;
    const int lane = tid & 63;
    const int nt   = tid >> 6;            // wave = N-tile, 0..5
    const int cgrp = lane & 15;
    const int kgrp = lane >> 4;

    // xs[hl][p][ci] bf16, p = t+3 padded coord. 6912 B -> 5 blocks/CU fit.
    __shared__ __align__(16) short xs[4 * 36 * 24];

    // ---- x staging: issue all 9 global dwords first (maximum MLP)
    float v0r[5], v1r[5];
#pragma unroll
    for (int it = 0; it < 5; ++it) {
        const int idx = tid + it * 384;
        if (idx < 1728) {
            const int p  = idx % 36;
            const int r  = idx / 36;
            const int cp = r % 12;
            const int hl = r / 12;
            const int ws = p - 3;
            const int rsrc = (4 * ht + hl + 27) % 28;   // (output row - 1) mod 28
            float a0 = 0.0f, a1 = 0.0f;
            if (ws >= 0 && ws < W_) {
                const size_t base =
                    ((size_t)(b * 48 + g * CIN_ + cp * 2) * H_ + rsrc) * W_ + ws;
                a0 = x[base];
                a1 = x[base + (size_t)HW_];
            }
            v0r[it] = a0; v1r[it] = a1;
        }
    }

    // ---- B fragments: 6 L2-hot dwordx4 -> 24 VGPR (overlap with x loads)
    short8 br[KSTEPS];
#pragma unroll
    for (int ks = 0; ks < KSTEPS; ++ks)
        br[ks] = wfg[(ks * NT_ + nt) * 64 + lane];

    // ---- convert + LDS write (single v_cvt_pk_bf16_f32 per dword)
#pragma unroll
    for (int it = 0; it < 5; ++it) {
        const int idx = tid + it * 384;
        if (idx < 1728) {
            const int p  = idx % 36;
            const int r  = idx / 36;
            const int cp = r % 12;
            const int hl = r / 12;
            ((unsigned*)xs)[(hl * 36 + p) * 12 + cp] = cvt_pk_bf16(v0r[it], v1r[it]);
        }
    }
    __syncthreads();

    // Per-lane k-step LDS offsets (A side of the shared k permutation)
    int koff[KSTEPS];
#pragma unroll
    for (int ks = 0; ks < KSTEPS; ++ks) {
        const int q   = ks * 4 + kgrp;
        const int k   = (q * 11) >> 5;
        const int ci0 = (q - 3 * k) * 8;
        koff[ks] = k * 24 + ci0;
    }

    const int c_out = nt * 16 + cgrp;
    float* cbase = out + ((size_t)(b * 192 + g * COUT_ + c_out)) * HW_;

#pragma unroll
    for (int mt = 0; mt < MT_; ++mt) {
        const int mA = mt * 16 + cgrp;
        const int hA = mA / 28;
        const int tA = mA - hA * 28;
        const int abase = (hA * 36 + tA) * 24;
        float4v acc = (float4v)(0.0f);
#pragma unroll
        for (int ks = 0; ks < KSTEPS; ++ks) {
            const short8 a = *(const short8*)&xs[abase + koff[ks]];
            acc = __builtin_amdgcn_mfma_f32_16x16x32_bf16(a, br[ks], acc, 0, 0, 0);
        }
        // D-quad j=0..3 = 4 consecutive t in one h-row (m0 % 4 == 0, 4 | 28)
        const int m0 = mt * 16 + kgrp * 4;
        const int hl = m0 / 28;
        const int t0 = m0 - hl * 28;
        const int hd = 4 * ht + hl;       // output row (roll absorbed in rsrc)
        float4 v; v.x = acc[0]; v.y = acc[1]; v.z = acc[2]; v.w = acc[3];
        *(float4*)&cbase[hd * W_ + t0] = v;
    }
}

extern "C" void kernel_launch(void* const* d_in, const int* in_sizes, int n_in,
                              void* d_out, int out_size, void* d_ws, size_t ws_size,
                              hipStream_t stream) {
    const float* x = (const float*)d_in[0];
    const float* w = (const float*)d_in[1];
    float* out = (float*)d_out;
    short8* wf = (short8*)d_ws;           // 36*64*16B = 36864 B

    wfrag_kernel<<<36, 64, 0, stream>>>(w, wf);
    conv_mfma_kernel<<<B_ * 2 * 7, 384, 0, stream>>>(x, wf, out);
}